// Round 8
// baseline (519.809 us; speedup 1.0000x reference)
//
#include <hip/hip_runtime.h>

typedef __bf16 bf16;
typedef __attribute__((ext_vector_type(8))) __bf16 bf16x8;
typedef __attribute__((ext_vector_type(4))) float f32x4;

#define LSTR 40   // LDS row stride in bf16 elems (80B) -> 2-way max bank alias (free)
#define BN_EPS 1e-5f

// ---------------- prep: transpose fp32 weights -> bf16 transposed in ws; zero cnt -------
__global__ __launch_bounds__(256) void k_prep(
        const float* __restrict__ W0, const float* __restrict__ W1, const float* __restrict__ W2,
        bf16* __restrict__ Wt0, bf16* __restrict__ Wt1, bf16* __restrict__ Wt2,
        int* __restrict__ cnt, int n)
{
    int i = blockIdx.x*256 + threadIdx.x;
    const int T = 768*64 + 8192;
    if (i < 768*64)            { int k = i>>6, n_ = i&63;                  Wt0[n_*768+k] = (bf16)W0[i]; }
    else if (i < 768*64+4096)  { int j = i-768*64;      int k=j>>6,c=j&63; Wt1[c*64+k]  = (bf16)W1[j]; }
    else if (i < T)            { int j = i-768*64-4096; int k=j>>6,c=j&63; Wt2[c*64+k]  = (bf16)W2[j]; }
    int j = i - T;
    if (j >= 0 && j < n) cnt[j] = 0;      // self-loops handled inline in gat_agg
}

// ---------------- MFMA GEMM: A[M x K] @ Bt[64 x K] bf16 -> 64 cols --------------------
// MODE 0: epilogue bias+BN+ELU -> bf16 full-row out (h).
// MODE 1: raw -> SPLIT bf16 half-tables xwLo/xwHi (N x 32 each, L2-resident for agg)
//         + FUSED attention logits (H=8: head-sliced asLo/asHi/adLo/adHi [N x 4];
//           H=1: asLo/adLo [N]).
// ABF: A is bf16 (else fp32, converted in staging). Register-prefetch double buffer.
template<int MODE, bool ABF, int H>
__global__ __launch_bounds__(256) void k_gemm64(
        const void* __restrict__ Av, const bf16* __restrict__ Bt, int M, int K,
        const float* __restrict__ pb, const float* __restrict__ g, const float* __restrict__ bb,
        const float* __restrict__ mm, const float* __restrict__ vv,
        bf16* __restrict__ outB,
        bf16* __restrict__ xwLo, bf16* __restrict__ xwHi,
        float* __restrict__ asLo, float* __restrict__ asHi,
        float* __restrict__ adLo, float* __restrict__ adHi,
        const float* __restrict__ att_s, const float* __restrict__ att_d)
{
    __shared__ bf16 xs[64*LSTR];
    __shared__ bf16 bs[64*LSTR];
    __shared__ float sC[64], cC[64];

    int t = threadIdx.x;
    int w = t >> 6, lane = t & 63;
    int q = lane >> 4, l16 = lane & 15;
    int row0 = blockIdx.x * 64;
    int sRow = t >> 2, sK = (t & 3) * 8;

    auto loadA = [&](int k0) -> bf16x8 {
        bf16x8 xv;
        #pragma unroll
        for (int i = 0; i < 8; ++i) xv[i] = (bf16)0.f;
        int gr = row0 + sRow;
        if (gr < M) {
            if constexpr (ABF) {
                xv = *(const bf16x8*)((const bf16*)Av + (size_t)gr*K + k0 + sK);
            } else {
                const float* ap = (const float*)Av + (size_t)gr*K + k0 + sK;
                float4 f0 = *(const float4*)ap;
                float4 f1 = *(const float4*)(ap + 4);
                xv[0]=(bf16)f0.x; xv[1]=(bf16)f0.y; xv[2]=(bf16)f0.z; xv[3]=(bf16)f0.w;
                xv[4]=(bf16)f1.x; xv[5]=(bf16)f1.y; xv[6]=(bf16)f1.z; xv[7]=(bf16)f1.w;
            }
        }
        return xv;
    };
    auto loadB = [&](int k0) -> bf16x8 {
        return *(const bf16x8*)(Bt + (size_t)sRow*K + k0 + sK);
    };

    f32x4 acc[4];
    #pragma unroll
    for (int i = 0; i < 4; ++i) { acc[i][0]=0.f; acc[i][1]=0.f; acc[i][2]=0.f; acc[i][3]=0.f; }

    bf16x8 xv = loadA(0);
    bf16x8 bv = loadB(0);

    for (int k0 = 0; k0 < K; k0 += 32) {
        *(bf16x8*)(xs + sRow*LSTR + sK) = xv;
        *(bf16x8*)(bs + sRow*LSTR + sK) = bv;
        __syncthreads();
        if (k0 + 32 < K) {               // prefetch next tile during MFMA
            xv = loadA(k0 + 32);
            bv = loadB(k0 + 32);
        }
        // A frag: A[m=lane&15][k=q*8+j]; B frag: B[n=lane&15][k=q*8+j]
        bf16x8 af = *(bf16x8*)(xs + (w*16 + l16)*LSTR + q*8);
        #pragma unroll
        for (int tt = 0; tt < 4; ++tt) {
            bf16x8 bfr = *(bf16x8*)(bs + (tt*16 + l16)*LSTR + q*8);
            acc[tt] = __builtin_amdgcn_mfma_f32_16x16x32_bf16(af, bfr, acc[tt], 0, 0, 0);
        }
        __syncthreads();
    }

    if constexpr (MODE == 0) {
        if (t < 64) {
            float s = rsqrtf(vv[t] + BN_EPS) * g[t];
            sC[t] = s;
            cC[t] = (pb[t] - mm[t]) * s + bb[t];
        }
        __syncthreads();
    }

    // C/D: col = lane&15, row = q*4 + reg   [m89-verified]
    #pragma unroll
    for (int tt = 0; tt < 4; ++tt) {
        int col = tt*16 + l16;
        #pragma unroll
        for (int r = 0; r < 4; ++r) {
            int row = row0 + w*16 + q*4 + r;
            if (row < M) {
                float val = acc[tt][r];
                if constexpr (MODE == 0) {
                    val = val * sC[col] + cC[col];
                    val = val > 0.f ? val : __expf(val) - 1.f;   // ELU
                    outB[(size_t)row*64 + col] = (bf16)val;
                } else {
                    if (col < 32) xwLo[(size_t)row*32 + col]      = (bf16)val;
                    else          xwHi[(size_t)row*32 + col - 32] = (bf16)val;
                }
            }
        }
    }

    if constexpr (MODE == 1) {
        // fused attention logits from the fp32 accumulator (pre-bf16-rounding)
        #pragma unroll
        for (int r = 0; r < 4; ++r) {
            int row = row0 + w*16 + q*4 + r;
            if constexpr (H == 1) {
                float ps = 0.f, pd = 0.f;
                #pragma unroll
                for (int tt = 0; tt < 4; ++tt) {
                    int col = tt*16 + l16;
                    ps += acc[tt][r] * att_s[col];
                    pd += acc[tt][r] * att_d[col];
                }
                #pragma unroll
                for (int off = 1; off < 16; off <<= 1) {
                    ps += __shfl_xor(ps, off);
                    pd += __shfl_xor(pd, off);
                }
                if (l16 == 0 && row < M) { asLo[row] = ps; adLo[row] = pd; }
            } else {
                float ps[4], pd[4];
                #pragma unroll
                for (int tt = 0; tt < 4; ++tt) {
                    int col = tt*16 + l16;          // head = col>>3 = 2*tt + (l16>>3)
                    ps[tt] = acc[tt][r] * att_s[col];
                    pd[tt] = acc[tt][r] * att_d[col];
                }
                #pragma unroll
                for (int off = 1; off < 8; off <<= 1) {
                    #pragma unroll
                    for (int tt = 0; tt < 4; ++tt) {
                        ps[tt] += __shfl_xor(ps[tt], off);
                        pd[tt] += __shfl_xor(pd[tt], off);
                    }
                }
                if ((l16 & 7) == 0 && row < M) {
                    int hb = l16 >> 3;
                    #pragma unroll
                    for (int tt = 0; tt < 4; ++tt) {
                        int head = 2*tt + hb;       // 0..7
                        if (head < 4) { asLo[row*4 + head]     = ps[tt]; adLo[row*4 + head]     = pd[tt]; }
                        else          { asHi[row*4 + head - 4] = ps[tt]; adHi[row*4 + head - 4] = pd[tt]; }
                    }
                }
            }
        }
    }
}

// ---------------- CSR build (edges only; self-loops inline in gat_agg) ----------------
__global__ __launch_bounds__(256) void k_count(const int* __restrict__ dst, int E, int* cnt) {
    int i = blockIdx.x*256 + threadIdx.x;
    if (i < E) atomicAdd(&cnt[dst[i]], 1);
}
__global__ __launch_bounds__(256) void k_scan_block(const int* __restrict__ cnt,
        int* __restrict__ rp, int* __restrict__ bsum, int n) {
    __shared__ int s[256];
    int t = threadIdx.x, v = blockIdx.x*256 + t;
    int x = (v < n) ? cnt[v] : 0;
    s[t] = x; __syncthreads();
    for (int off = 1; off < 256; off <<= 1) {
        int y = (t >= off) ? s[t-off] : 0;
        __syncthreads();
        s[t] += y;
        __syncthreads();
    }
    if (v < n) rp[v+1] = s[t];
    if (t == 255) bsum[blockIdx.x] = s[255];
}
__global__ __launch_bounds__(256) void k_scan_bsum(int* bsum, int nb) {
    __shared__ int s[256];
    int t = threadIdx.x;
    int x = (t < nb) ? bsum[t] : 0;
    s[t] = x; __syncthreads();
    for (int off = 1; off < 256; off <<= 1) {
        int y = (t >= off) ? s[t-off] : 0;
        __syncthreads();
        s[t] += y;
        __syncthreads();
    }
    if (t < nb) bsum[t] = s[t] - x;        // exclusive
}
__global__ __launch_bounds__(256) void k_finalize(int* __restrict__ rp, const int* __restrict__ bsum,
        const int* __restrict__ cnt, int* __restrict__ cursor, int n) {
    int v = blockIdx.x*256 + threadIdx.x;
    if (v < n) {
        int val = rp[v+1] + bsum[v >> 8];
        rp[v+1] = val;
        cursor[v] = val - cnt[v];          // = rp[v]
        if (v == 0) rp[0] = 0;
    }
}
__global__ __launch_bounds__(256) void k_scatter(const int* __restrict__ src, const int* __restrict__ dst,
        int E, int* __restrict__ cursor, int* __restrict__ in_src) {
    int i = blockIdx.x*256 + threadIdx.x;
    if (i < E) {
        int pos = atomicAdd(&cursor[dst[i]], 1);
        in_src[pos] = src[i];
    }
}

// ---------------- GAT aggregation, feature-half pass (table is L2-resident) -------------
// PASS selects features [PASS*32, PASS*32+32). xwh is the N x 32 half-table.
// lane = 32*half + f : half 0 processes even edge slots, half 1 odd slots; fold via shfl(32).
// H=8: a_src/a_dst are head-sliced [N x 4] for this pass. H=1: [N].
// CLS: PASS 0 writes out (= partial + b), PASS 1 accumulates (+=); ordered dispatches.
template<int H, bool CLS, int PASS>
__global__ __launch_bounds__(256) void k_gat_agg(const bf16* __restrict__ xwh,
        const float* __restrict__ a_src, const float* __restrict__ a_dst,
        const int* __restrict__ rp, const int* __restrict__ in_src,
        const float* __restrict__ bias,
        const float* __restrict__ g, const float* __restrict__ bb,
        const float* __restrict__ mm, const float* __restrict__ vv,
        const bf16* __restrict__ resid, bf16* __restrict__ outB, float* __restrict__ outF,
        const float* __restrict__ clsW, const float* __restrict__ clsb, int n)
{
    int wv = (blockIdx.x*256 + threadIdx.x) >> 6;
    int lane = threadIdx.x & 63;
    if (wv >= n) return;
    int half = lane >> 5, f = lane & 31;
    int hh = (H == 8) ? (f >> 3) : 0;              // head within pass slice
    float adst = (H == 8) ? a_dst[wv*4 + hh] : a_dst[wv];

    float acc = 0.f, den = 0.f;
    if (half == 0) {                                // self-loop (half 0 only)
        float as = (H == 8) ? a_src[wv*4 + hh] : a_src[wv];
        float a = as + adst; a = (a > 0.f) ? a : 0.2f*a;
        float ex = __expf(a);
        acc = ex * (float)xwh[(size_t)wv*32 + f];
        den = ex;
    }

    int beg = rp[wv], end = rp[wv+1];
    int idx = beg + half;                           // stride-2 partition between halves
    for (; idx + 6 < end; idx += 8) {               // 4 edges per half in flight
        int u0 = in_src[idx], u1 = in_src[idx+2], u2 = in_src[idx+4], u3 = in_src[idx+6];
        float s0, s1, s2, s3;
        if (H == 8) {
            s0 = a_src[u0*4 + hh]; s1 = a_src[u1*4 + hh];
            s2 = a_src[u2*4 + hh]; s3 = a_src[u3*4 + hh];
        } else {
            s0 = a_src[u0]; s1 = a_src[u1]; s2 = a_src[u2]; s3 = a_src[u3];
        }
        float x0 = (float)xwh[(size_t)u0*32 + f];
        float x1 = (float)xwh[(size_t)u1*32 + f];
        float x2 = (float)xwh[(size_t)u2*32 + f];
        float x3 = (float)xwh[(size_t)u3*32 + f];
        float a0 = s0 + adst; a0 = (a0 > 0.f) ? a0 : 0.2f*a0; float e0 = __expf(a0);
        float a1 = s1 + adst; a1 = (a1 > 0.f) ? a1 : 0.2f*a1; float e1 = __expf(a1);
        float a2 = s2 + adst; a2 = (a2 > 0.f) ? a2 : 0.2f*a2; float e2 = __expf(a2);
        float a3 = s3 + adst; a3 = (a3 > 0.f) ? a3 : 0.2f*a3; float e3 = __expf(a3);
        acc += e0*x0 + e1*x1 + e2*x2 + e3*x3;
        den += e0 + e1 + e2 + e3;
    }
    for (; idx < end; idx += 2) {
        int u = in_src[idx];
        float s = (H == 8) ? a_src[u*4 + hh] : a_src[u];
        float a = s + adst; a = (a > 0.f) ? a : 0.2f*a;
        float ex = __expf(a);
        acc += ex * (float)xwh[(size_t)u*32 + f];
        den += ex;
    }
    // fold the two edge-slot halves (lanes l and l^32 hold the same feature f)
    acc += __shfl_xor(acc, 32);
    den += __shfl_xor(den, 32);

    int c = PASS*32 + f;                            // global feature index
    float val = acc/den + bias[c];
    float sc = rsqrtf(vv[c] + BN_EPS) * g[c];
    val = (val - mm[c]) * sc + bb[c];
    val += (float)resid[(size_t)wv*64 + c];
    val = (val > 0.f) ? val : __expf(val) - 1.f;    // ELU

    if constexpr (!CLS) {
        if (half == 0) outB[(size_t)wv*64 + c] = (bf16)val;
    } else {
        // partial classifier over this pass's 32 features
        float keep = 0.f;
        #pragma unroll
        for (int o = 0; o < 8; ++o) {
            float p = val * clsW[c*8 + o];
            #pragma unroll
            for (int off = 1; off < 32; off <<= 1) p += __shfl_xor(p, off);
            if (f == o) keep = p;
        }
        if (half == 0 && f < 8) {
            if (PASS == 0) outF[(size_t)wv*8 + f] = keep + clsb[f];
            else           outF[(size_t)wv*8 + f] += keep;
        }
    }
}

// ---------------- host ----------------
extern "C" void kernel_launch(void* const* d_in, const int* in_sizes, int n_in,
                              void* d_out, int out_size, void* d_ws, size_t ws_size,
                              hipStream_t stream)
{
    const float* x      = (const float*)d_in[0];
    const int*   ei     = (const int*)  d_in[1];
    const float* proj_W = (const float*)d_in[2];
    const float* proj_b = (const float*)d_in[3];
    const float* bn1_g  = (const float*)d_in[4];
    const float* bn1_b  = (const float*)d_in[5];
    const float* bn1_m  = (const float*)d_in[6];
    const float* bn1_v  = (const float*)d_in[7];
    const float* bn2_g  = (const float*)d_in[8];
    const float* bn2_b  = (const float*)d_in[9];
    const float* bn2_m  = (const float*)d_in[10];
    const float* bn2_v  = (const float*)d_in[11];
    const float* bn3_g  = (const float*)d_in[12];
    const float* bn3_b  = (const float*)d_in[13];
    const float* bn3_m  = (const float*)d_in[14];
    const float* bn3_v  = (const float*)d_in[15];
    const float* W1     = (const float*)d_in[16];
    const float* att_s1 = (const float*)d_in[17];
    const float* att_d1 = (const float*)d_in[18];
    const float* b1     = (const float*)d_in[19];
    const float* W2     = (const float*)d_in[20];
    const float* att_s2 = (const float*)d_in[21];
    const float* att_d2 = (const float*)d_in[22];
    const float* b2     = (const float*)d_in[23];
    const float* cls_W  = (const float*)d_in[24];
    const float* cls_b  = (const float*)d_in[25];

    const int N = in_sizes[0] / 768;
    const int E = in_sizes[1] / 2;
    const int* srce = ei;
    const int* dste = ei + E;

    // workspace carve
    char* p = (char*)d_ws;
    auto carve = [&](size_t bytes) -> void* {
        void* r = (void*)p;
        p += (bytes + 255) & ~(size_t)255;
        return r;
    };
    bf16*  Wt0    = (bf16*) carve((size_t)64*768*2);
    bf16*  Wt1    = (bf16*) carve((size_t)64*64*2);
    bf16*  Wt2    = (bf16*) carve((size_t)64*64*2);
    bf16*  h0b    = (bf16*) carve((size_t)N*64*2);
    bf16*  h1b    = (bf16*) carve((size_t)N*64*2);
    bf16*  xwLo   = (bf16*) carve((size_t)N*32*2);
    bf16*  xwHi   = (bf16*) carve((size_t)N*32*2);
    float* as0    = (float*)carve((size_t)N*4*4);
    float* as1    = (float*)carve((size_t)N*4*4);
    float* ad0    = (float*)carve((size_t)N*4*4);
    float* ad1    = (float*)carve((size_t)N*4*4);
    int*   cnt    = (int*)  carve((size_t)N*4);
    int*   rp     = (int*)  carve((size_t)(N+1)*4);
    int*   cursor = (int*)  carve((size_t)N*4);
    int*   bsum   = (int*)  carve(1024);
    int*   in_src = (int*)  carve((size_t)E*4);

    const int nb = (N + 255) / 256;
    const int nw = (N + 3) / 4;
    const int PREP = 768*64 + 8192;

    k_prep<<<(PREP + N + 255)/256, 256, 0, stream>>>(proj_W, W1, W2, Wt0, Wt1, Wt2, cnt, N);

    // CSR (edges only; shared by both GAT layers)
    k_count<<<(E + 255)/256, 256, 0, stream>>>(dste, E, cnt);
    k_scan_block<<<nb, 256, 0, stream>>>(cnt, rp, bsum, N);
    k_scan_bsum<<<1, 256, 0, stream>>>(bsum, nb);
    k_finalize<<<nb, 256, 0, stream>>>(rp, bsum, cnt, cursor, N);
    k_scatter<<<(E + 255)/256, 256, 0, stream>>>(srce, dste, E, cursor, in_src);

    // h0 = elu(bn1(x @ proj_W + proj_b))  [bf16]
    k_gemm64<0, false, 1><<<(N + 63)/64, 256, 0, stream>>>(x, Wt0, N, 768,
            proj_b, bn1_g, bn1_b, bn1_m, bn1_v, h0b,
            nullptr, nullptr, nullptr, nullptr, nullptr, nullptr, nullptr, nullptr);

    // ---- GAT layer 1 (H=8): split xw + head-sliced logits, two L2-resident agg passes ----
    k_gemm64<1, true, 8><<<(N + 63)/64, 256, 0, stream>>>(h0b, Wt1, N, 64,
            nullptr, nullptr, nullptr, nullptr, nullptr, nullptr,
            xwLo, xwHi, as0, as1, ad0, ad1, att_s1, att_d1);
    k_gat_agg<8, false, 0><<<nw, 256, 0, stream>>>(xwLo, as0, ad0, rp, in_src,
            b1, bn2_g, bn2_b, bn2_m, bn2_v, h0b, h1b, nullptr, nullptr, nullptr, N);
    k_gat_agg<8, false, 1><<<nw, 256, 0, stream>>>(xwHi, as1, ad1, rp, in_src,
            b1, bn2_g, bn2_b, bn2_m, bn2_v, h0b, h1b, nullptr, nullptr, nullptr, N);

    // ---- GAT layer 2 (H=1), classifier fused + accumulated across the two passes ----
    k_gemm64<1, true, 1><<<(N + 63)/64, 256, 0, stream>>>(h1b, Wt2, N, 64,
            nullptr, nullptr, nullptr, nullptr, nullptr, nullptr,
            xwLo, xwHi, as0, nullptr, ad0, nullptr, att_s2, att_d2);
    k_gat_agg<1, true, 0><<<nw, 256, 0, stream>>>(xwLo, as0, ad0, rp, in_src,
            b2, bn3_g, bn3_b, bn3_m, bn3_v, h1b, nullptr, (float*)d_out, cls_W, cls_b, N);
    k_gat_agg<1, true, 1><<<nw, 256, 0, stream>>>(xwHi, as0, ad0, rp, in_src,
            b2, bn3_g, bn3_b, bn3_m, bn3_v, h1b, nullptr, (float*)d_out, cls_W, cls_b, N);
}